// Round 5
// baseline (338.573 us; speedup 1.0000x reference)
//
#include <hip/hip_runtime.h>

#define THREADS 512

typedef short bf8 __attribute__((ext_vector_type(8)));
typedef float f32x4 __attribute__((ext_vector_type(4)));

__device__ __forceinline__ unsigned bf_rne(float f) {
  unsigned u = __float_as_uint(f);
  return (u + 0x7fffu + ((u >> 16) & 1u)) >> 16;
}
__device__ __forceinline__ float bf_f(unsigned h) { return __uint_as_float(h << 16); }

// swizzled Hs word index: row r (0..27), col c (0..511)
__device__ __forceinline__ int hsw(int r, int c) {
  const int key = (r & 7) ^ (r >> 3);
  return r * 512 + (((c >> 3) ^ key) << 3) + (c & 7);
}

struct S3 { bf8 a, b, c; };
__device__ __forceinline__ S3 split3(float4 lo, float4 hi) {
  float v[8] = {lo.x, lo.y, lo.z, lo.w, hi.x, hi.y, hi.z, hi.w};
  S3 s;
#pragma unroll
  for (int e = 0; e < 8; ++e) {
    const unsigned a = bf_rne(v[e]); const float fa = bf_f(a);
    const float r1 = v[e] - fa;
    const unsigned b = bf_rne(r1);   const float fb = bf_f(b);
    const unsigned c = bf_rne(r1 - fb);
    s.a[e] = (short)a; s.b[e] = (short)b; s.c[e] = (short)c;
  }
  return s;
}
struct S2 { bf8 a, b; };
__device__ __forceinline__ S2 split2(float4 lo, float4 hi) {
  float v[8] = {lo.x, lo.y, lo.z, lo.w, hi.x, hi.y, hi.z, hi.w};
  S2 s;
#pragma unroll
  for (int e = 0; e < 8; ++e) {
    const unsigned a = bf_rne(v[e]); const float fa = bf_f(a);
    const unsigned b = bf_rne(v[e] - fa);
    s.a[e] = (short)a; s.b[e] = (short)b;
  }
  return s;
}

// ---- prep: W [512][28] f32 -> fragment-ready 3-level split-bf16 in d_ws ----
// Wfrag layout: [L][T][lane][e] ushort, e: k = 4g+e (e<4) | 16+4g+(e-4), g=lane>>4
__global__ void prep_wfrag(const float* __restrict__ W, unsigned short* __restrict__ wf) {
  const int id = blockIdx.x * 256 + threadIdx.x;   // 0..2047
  if (id >= 2048) return;
  const int T = id >> 6, l = id & 63, g = (l >> 4) & 3, li = l & 15;
  const int col = 16 * T + li;                     // W row index (H column)
#pragma unroll
  for (int e = 0; e < 8; ++e) {
    const int k = (e < 4) ? (4 * g + e) : (16 + 4 * g + (e - 4));
    const float v = (k < 28) ? W[col * 28 + k] : 0.f;
    const unsigned a = bf_rne(v); const float fa = bf_f(a);
    const float r1 = v - fa;
    const unsigned b = bf_rne(r1); const float fb = bf_f(b);
    const unsigned c = bf_rne(r1 - fb);
    wf[((0 * 32 + T) * 64 + l) * 8 + e] = (unsigned short)a;
    wf[((1 * 32 + T) * 64 + l) * 8 + e] = (unsigned short)b;
    wf[((2 * 32 + T) * 64 + l) * 8 + e] = (unsigned short)c;
  }
}

// One block = one sample; 512 threads = 8 waves.
__global__ __launch_bounds__(THREADS, 4) void elm_kernel(
    const float* __restrict__ x, const unsigned short* __restrict__ wf,
    const float* __restrict__ bias, float* __restrict__ Xout,
    float* __restrict__ Bout)
{
  __shared__ float Hs[14336];   // H[28][512] swizzled; later B staging [512][28]
  __shared__ float xY[1152];    // x rows [28][36] (cols 28-35 + rows 28-31 zero); then Y^T
  __shared__ float Gc[896];     // G[28][32]
  // 65536 B total

  const int tid = threadIdx.x;
  const int n   = blockIdx.x;
  const int w   = tid >> 6, l = tid & 63, g = l >> 4, li = l & 15;
  const int mw  = w >> 2, Tb = 8 * (w & 3);
  const float* xi = x + (size_t)n * 784;

  // ---- 0. init: zero Gc, zero xY pads, load x, write X = x ----
  Gc[tid & 511] = 0.f;                 // 0..511
  if (tid < 384) Gc[512 + tid] = 0.f;  // 512..895
  if (tid < 28) {                      // col pads 28..35 of rows 0..27
    *reinterpret_cast<float4*>(&xY[tid * 36 + 28]) = float4{0, 0, 0, 0};
    *reinterpret_cast<float4*>(&xY[tid * 36 + 32]) = float4{0, 0, 0, 0};
  } else if (tid < 64) {               // pad rows 28..31: words 1008..1151
    *reinterpret_cast<float4*>(&xY[1008 + (tid - 28) * 4]) = float4{0, 0, 0, 0};
  } else if (tid < 260) {              // x load + X copy (196 float4)
    const int t = tid - 64;
    const float4 v = reinterpret_cast<const float4*>(xi)[t];
    reinterpret_cast<float4*>(Xout + (size_t)n * 784)[t] = v;
    const int r = t / 7, c4 = t - r * 7;
    *reinterpret_cast<float4*>(&xY[r * 36 + 4 * c4]) = v;
  }
  __syncthreads();

  // ---- 1. H = sigmoid(x W^T + b) via 6-term split-bf16 MFMA ----
  {
    const int arow = 16 * mw + li;     // 0..31 (pads give zeros)
    const float4 xa = *reinterpret_cast<const float4*>(&xY[arow * 36 + 4 * g]);
    const float4 xb = *reinterpret_cast<const float4*>(&xY[arow * 36 + 16 + 4 * g]);
    const S3 A = split3(xa, xb);
    const uint4* wf4 = reinterpret_cast<const uint4*>(wf);
#pragma unroll
    for (int t = 0; t < 8; ++t) {
      const int T = Tb + t;
      const bf8 B1 = __builtin_bit_cast(bf8, wf4[(0 * 32 + T) * 64 + l]);
      const bf8 B2 = __builtin_bit_cast(bf8, wf4[(1 * 32 + T) * 64 + l]);
      const bf8 B3 = __builtin_bit_cast(bf8, wf4[(2 * 32 + T) * 64 + l]);
      f32x4 acc = {0.f, 0.f, 0.f, 0.f};
      acc = __builtin_amdgcn_mfma_f32_16x16x32_bf16(A.a, B1, acc, 0, 0, 0);
      acc = __builtin_amdgcn_mfma_f32_16x16x32_bf16(A.a, B2, acc, 0, 0, 0);
      acc = __builtin_amdgcn_mfma_f32_16x16x32_bf16(A.b, B1, acc, 0, 0, 0);
      acc = __builtin_amdgcn_mfma_f32_16x16x32_bf16(A.a, B3, acc, 0, 0, 0);
      acc = __builtin_amdgcn_mfma_f32_16x16x32_bf16(A.c, B1, acc, 0, 0, 0);
      acc = __builtin_amdgcn_mfma_f32_16x16x32_bf16(A.b, B2, acc, 0, 0, 0);
      const float bv = bias[16 * T + li];
#pragma unroll
      for (int i = 0; i < 4; ++i) {
        const int ro = 16 * mw + 4 * g + i;
        if (ro < 28) {
          const float a = acc[i] + bv;
          Hs[hsw(ro, 16 * T + li)] = 1.0f / (1.0f + __expf(-a));
        }
      }
    }
  }
  __syncthreads();

  // ---- 2. G = H H^T : wave w owns K-steps s=2w,2w+1; 6-term split ----
  {
    f32x4 d00 = {0,0,0,0}, d01 = {0,0,0,0}, d10 = {0,0,0,0}, d11 = {0,0,0,0};
#pragma unroll
    for (int ss = 0; ss < 2; ++ss) {
      const int s = 2 * w + ss;
      const int r0 = li, r1 = 16 + li;
      float4 z = {0, 0, 0, 0};
      const float4 a0 = *reinterpret_cast<const float4*>(&Hs[hsw(r0, 32 * s + 4 * g)]);
      const float4 a1 = *reinterpret_cast<const float4*>(&Hs[hsw(r0, 32 * s + 16 + 4 * g)]);
      const float4 b0 = (r1 < 28) ? *reinterpret_cast<const float4*>(&Hs[hsw(r1 < 28 ? r1 : 0, 32 * s + 4 * g)]) : z;
      const float4 b1 = (r1 < 28) ? *reinterpret_cast<const float4*>(&Hs[hsw(r1 < 28 ? r1 : 0, 32 * s + 16 + 4 * g)]) : z;
      const S3 F0 = split3(a0, a1);
      const S3 F1 = split3(b0, b1);
      // tile (m,n): D += Fm x Fn, 6 terms each
      d00 = __builtin_amdgcn_mfma_f32_16x16x32_bf16(F0.a, F0.a, d00, 0, 0, 0);
      d00 = __builtin_amdgcn_mfma_f32_16x16x32_bf16(F0.a, F0.b, d00, 0, 0, 0);
      d00 = __builtin_amdgcn_mfma_f32_16x16x32_bf16(F0.b, F0.a, d00, 0, 0, 0);
      d00 = __builtin_amdgcn_mfma_f32_16x16x32_bf16(F0.a, F0.c, d00, 0, 0, 0);
      d00 = __builtin_amdgcn_mfma_f32_16x16x32_bf16(F0.c, F0.a, d00, 0, 0, 0);
      d00 = __builtin_amdgcn_mfma_f32_16x16x32_bf16(F0.b, F0.b, d00, 0, 0, 0);
      d01 = __builtin_amdgcn_mfma_f32_16x16x32_bf16(F0.a, F1.a, d01, 0, 0, 0);
      d01 = __builtin_amdgcn_mfma_f32_16x16x32_bf16(F0.a, F1.b, d01, 0, 0, 0);
      d01 = __builtin_amdgcn_mfma_f32_16x16x32_bf16(F0.b, F1.a, d01, 0, 0, 0);
      d01 = __builtin_amdgcn_mfma_f32_16x16x32_bf16(F0.a, F1.c, d01, 0, 0, 0);
      d01 = __builtin_amdgcn_mfma_f32_16x16x32_bf16(F0.c, F1.a, d01, 0, 0, 0);
      d01 = __builtin_amdgcn_mfma_f32_16x16x32_bf16(F0.b, F1.b, d01, 0, 0, 0);
      d10 = __builtin_amdgcn_mfma_f32_16x16x32_bf16(F1.a, F0.a, d10, 0, 0, 0);
      d10 = __builtin_amdgcn_mfma_f32_16x16x32_bf16(F1.a, F0.b, d10, 0, 0, 0);
      d10 = __builtin_amdgcn_mfma_f32_16x16x32_bf16(F1.b, F0.a, d10, 0, 0, 0);
      d10 = __builtin_amdgcn_mfma_f32_16x16x32_bf16(F1.a, F0.c, d10, 0, 0, 0);
      d10 = __builtin_amdgcn_mfma_f32_16x16x32_bf16(F1.c, F0.a, d10, 0, 0, 0);
      d10 = __builtin_amdgcn_mfma_f32_16x16x32_bf16(F1.b, F0.b, d10, 0, 0, 0);
      d11 = __builtin_amdgcn_mfma_f32_16x16x32_bf16(F1.a, F1.a, d11, 0, 0, 0);
      d11 = __builtin_amdgcn_mfma_f32_16x16x32_bf16(F1.a, F1.b, d11, 0, 0, 0);
      d11 = __builtin_amdgcn_mfma_f32_16x16x32_bf16(F1.b, F1.a, d11, 0, 0, 0);
      d11 = __builtin_amdgcn_mfma_f32_16x16x32_bf16(F1.a, F1.c, d11, 0, 0, 0);
      d11 = __builtin_amdgcn_mfma_f32_16x16x32_bf16(F1.c, F1.a, d11, 0, 0, 0);
      d11 = __builtin_amdgcn_mfma_f32_16x16x32_bf16(F1.b, F1.b, d11, 0, 0, 0);
    }
#pragma unroll
    for (int i = 0; i < 4; ++i) {
      const int ra = 4 * g + i, rb = 16 + 4 * g + i;
      atomicAdd(&Gc[ra * 32 + li], d00[i]);
      atomicAdd(&Gc[ra * 32 + 16 + li], d01[i]);
      if (rb < 28) {
        atomicAdd(&Gc[rb * 32 + li], d10[i]);
        atomicAdd(&Gc[rb * 32 + 16 + li], d11[i]);
      }
    }
  }
  __syncthreads();

  // ---- 3. solve G Y = x : Gauss-Jordan on wave 0 ----
  if (tid < 64) {
    const int j = tid;
    float col[28];
#pragma unroll
    for (int r = 0; r < 28; ++r) {
      float v = 0.f;
      if (j < 28)      v = Gc[r * 32 + j];
      else if (j < 56) v = xY[r * 36 + (j - 28)];
      col[r] = v;
    }
#pragma unroll
    for (int k = 0; k < 28; ++k) {
      const float piv = __shfl(col[k], k);
      const float pivinv = 1.0f / piv;
      col[k] *= pivinv;
#pragma unroll
      for (int r = 0; r < 28; ++r) {
        if (r == k) continue;
        const float m = __shfl(col[r], k);
        col[r] -= m * col[k];
      }
    }
    if (j >= 28 && j < 56) {           // Y^T: xY[c*36 + a] = Y[a][c]
      const int c = j - 28;
#pragma unroll
      for (int r = 0; r < 28; ++r) xY[c * 36 + r] = col[r];
    }
  }
  __syncthreads();

  // ---- 4. Bt = Y^T H (3-term 2-split), results in regs ----
  f32x4 bt[8];
  {
    const int crow = 16 * mw + li;     // 0..31, pads zero
    const float4 ya = *reinterpret_cast<const float4*>(&xY[crow * 36 + 4 * g]);
    const float4 yb = *reinterpret_cast<const float4*>(&xY[crow * 36 + 16 + 4 * g]);
    const S2 Y = split2(ya, yb);
#pragma unroll
    for (int t = 0; t < 8; ++t) {
      const int col = 16 * (Tb + t) + li;
      float4 hlo, hhi;
      hlo.x = Hs[hsw(4 * g + 0, col)];
      hlo.y = Hs[hsw(4 * g + 1, col)];
      hlo.z = Hs[hsw(4 * g + 2, col)];
      hlo.w = Hs[hsw(4 * g + 3, col)];
      hhi.x = (16 + 4 * g + 0 < 28) ? Hs[hsw(16 + 4 * g + 0, col)] : 0.f;
      hhi.y = (16 + 4 * g + 1 < 28) ? Hs[hsw(16 + 4 * g + 1, col)] : 0.f;
      hhi.z = (16 + 4 * g + 2 < 28) ? Hs[hsw(16 + 4 * g + 2, col)] : 0.f;
      hhi.w = (16 + 4 * g + 3 < 28) ? Hs[hsw(16 + 4 * g + 3, col)] : 0.f;
      const S2 Hb = split2(hlo, hhi);
      f32x4 acc = {0.f, 0.f, 0.f, 0.f};
      acc = __builtin_amdgcn_mfma_f32_16x16x32_bf16(Y.a, Hb.a, acc, 0, 0, 0);
      acc = __builtin_amdgcn_mfma_f32_16x16x32_bf16(Y.a, Hb.b, acc, 0, 0, 0);
      acc = __builtin_amdgcn_mfma_f32_16x16x32_bf16(Y.b, Hb.a, acc, 0, 0, 0);
      bt[t] = acc;
    }
  }
  __syncthreads();   // all Hs reads complete -> reuse as B staging

  // ---- 5. stage Bt into Bs[h][c] (= Hs region), then coalesced flush ----
  {
    const int c0 = 16 * mw + 4 * g;
    if (c0 < 28) {
#pragma unroll
      for (int t = 0; t < 8; ++t) {
        const int h = 16 * (Tb + t) + li;
        float4 v; v.x = bt[t][0]; v.y = bt[t][1]; v.z = bt[t][2]; v.w = bt[t][3];
        *reinterpret_cast<float4*>(&Hs[h * 28 + c0]) = v;
      }
    }
  }
  __syncthreads();
  {
    const float4* Bs4 = reinterpret_cast<const float4*>(Hs);
    float4* BO4 = reinterpret_cast<float4*>(Bout + (size_t)n * 14336);
#pragma unroll
    for (int k = 0; k < 7; ++k) BO4[k * 512 + tid] = Bs4[k * 512 + tid];
  }
}

extern "C" void kernel_launch(void* const* d_in, const int* in_sizes, int n_in,
                              void* d_out, int out_size, void* d_ws, size_t ws_size,
                              hipStream_t stream) {
  const float* x = (const float*)d_in[0];
  const float* W = (const float*)d_in[1];
  const float* b = (const float*)d_in[2];
  const int N = in_sizes[0] / 784;               // 4096 samples
  float* Xout = (float*)d_out;                   // [N,1,28,28]
  float* Bout = Xout + (size_t)N * 784;          // [N,1,512,28]
  unsigned short* wf = (unsigned short*)d_ws;    // 98304 B
  prep_wfrag<<<8, 256, 0, stream>>>(W, wf);
  elm_kernel<<<N, THREADS, 0, stream>>>(x, wf, b, Xout, Bout);
}

// Round 6
// 209.849 us; speedup vs baseline: 1.6134x; 1.6134x over previous
//
#include <hip/hip_runtime.h>

#define THREADS 512

typedef _Float16 f16x8 __attribute__((ext_vector_type(8)));
typedef float f32x4 __attribute__((ext_vector_type(4)));

#define MFMA(A, B, C) __builtin_amdgcn_mfma_f32_16x16x32_f16(A, B, C, 0, 0, 0)

struct P16 { f16x8 hi, lo; };

__device__ __forceinline__ P16 split16(float4 a, float4 b) {
  float v[8] = {a.x, a.y, a.z, a.w, b.x, b.y, b.z, b.w};
  P16 p;
#pragma unroll
  for (int e = 0; e < 8; ++e) {
    const _Float16 h = (_Float16)v[e];
    const _Float16 lw = (_Float16)(v[e] - (float)h);
    p.hi[e] = h; p.lo[e] = lw;
  }
  return p;
}

__device__ __forceinline__ P16 unpackP(uint4 u0, uint4 u1) {
  unsigned uu[8] = {u0.x, u0.y, u0.z, u0.w, u1.x, u1.y, u1.z, u1.w};
  P16 p;
#pragma unroll
  for (int e = 0; e < 8; ++e) {
    p.hi[e] = __builtin_bit_cast(_Float16, (unsigned short)(uu[e] & 0xffffu));
    p.lo[e] = __builtin_bit_cast(_Float16, (unsigned short)(uu[e] >> 16));
  }
  return p;
}

__device__ __forceinline__ float sigm(float a) {
  return __builtin_amdgcn_rcpf(1.0f + __expf(-a));
}

__device__ __forceinline__ unsigned packh(float v) {
  const _Float16 h = (_Float16)v;
  const _Float16 lw = (_Float16)(v - (float)h);
  return (unsigned)__builtin_bit_cast(unsigned short, h) |
         ((unsigned)__builtin_bit_cast(unsigned short, lw) << 16);
}

// W [512][28] f32 -> f16 hi/lo fragment planes: wf[{0,1}*32 + T][lane] = uint4
// element e: k = 4g+e (e<4) | 16+4g+(e-4), g=lane>>4; W-col = 16T + (lane&15)
__global__ void prep_wfrag(const float* __restrict__ W, uint4* __restrict__ wf) {
  const int id = blockIdx.x * 256 + threadIdx.x;
  if (id >= 2048) return;
  const int T = id >> 6, l = id & 63, g = (l >> 4) & 3, li = l & 15;
  const int col = 16 * T + li;
  unsigned hi[8], lo[8];
#pragma unroll
  for (int e = 0; e < 8; ++e) {
    const int k = (e < 4) ? (4 * g + e) : (16 + 4 * g + (e - 4));
    const float v = (k < 28) ? W[col * 28 + k] : 0.0f;
    const _Float16 h = (_Float16)v;
    const _Float16 lw = (_Float16)(v - (float)h);
    hi[e] = __builtin_bit_cast(unsigned short, h);
    lo[e] = __builtin_bit_cast(unsigned short, lw);
  }
  uint4 uh, ul;
  uh.x = hi[0] | (hi[1] << 16); uh.y = hi[2] | (hi[3] << 16);
  uh.z = hi[4] | (hi[5] << 16); uh.w = hi[6] | (hi[7] << 16);
  ul.x = lo[0] | (lo[1] << 16); ul.y = lo[2] | (lo[3] << 16);
  ul.z = lo[4] | (lo[5] << 16); ul.w = lo[6] | (lo[7] << 16);
  wf[T * 64 + l] = uh;
  wf[(32 + T) * 64 + l] = ul;
}

// One block = one sample; 512 threads = 8 waves.
// H = sigmoid(xW^T+b) built chunk-wise (2 x 256 cols) as packed f16 hi/lo in LDS.
// G = H~ H~^T via 4-term f16 MFMA (exact product of represented H~, f32 accum).
// Y = G^-1 x (Gauss-Jordan, wave 0).  X = x (H full row-rank).  B = H~^T Y with
// H~ recomputed per tile -- MFMA output fragment IS the Bt B-operand fragment.
__global__ __launch_bounds__(THREADS, 6) void elm_kernel(
    const float* __restrict__ x, const uint4* __restrict__ wf,
    const float* __restrict__ bias, float* __restrict__ Xout,
    float* __restrict__ Bout)
{
  __shared__ __align__(16) unsigned Hc[8192]; // 32KB: H chunk / G scratch / B staging
  __shared__ __align__(16) float xs[1152];    // x [32][36], zero-padded
  __shared__ __align__(16) float Yt[1152];    // Y^T [32][36], zero-padded
  __shared__ __align__(16) float Gc[896];     // G [28][32]
  // total 45568 B -> 3 blocks/CU

  const int tid = threadIdx.x;
  const int n = blockIdx.x;
  const int w = tid >> 6, l = tid & 63, g = l >> 4, li = l & 15;
  const int tr = w >> 2, q = w & 3, tl = 2 * w; // tile-row, k-quarter, first tile
  const float* xi = x + (size_t)n * 784;

  // ---- 0. init: zero Yt + xs pads, load x, X = x ----
  if (tid < 288) reinterpret_cast<float4*>(Yt)[tid] = float4{0, 0, 0, 0};
  if (tid < 28) {
    *reinterpret_cast<float4*>(&xs[tid * 36 + 28]) = float4{0, 0, 0, 0};
    *reinterpret_cast<float4*>(&xs[tid * 36 + 32]) = float4{0, 0, 0, 0};
  } else if (tid < 64) {
    *reinterpret_cast<float4*>(&xs[1008 + (tid - 28) * 4]) = float4{0, 0, 0, 0};
  } else if (tid < 260) {
    const int t = tid - 64;
    const float4 v = reinterpret_cast<const float4*>(xi)[t];
    reinterpret_cast<float4*>(Xout + (size_t)n * 784)[t] = v;
    const int r = t / 7, c4 = t - r * 7;
    *reinterpret_cast<float4*>(&xs[r * 36 + 4 * c4]) = v;
  }
  __syncthreads();

  // ---- 1. x A-fragments (m-half 0: rows li; half 1: rows 16+li) ----
  P16 X0, X1;
  {
    const float4 a0 = *reinterpret_cast<const float4*>(&xs[li * 36 + 4 * g]);
    const float4 b0 = *reinterpret_cast<const float4*>(&xs[li * 36 + 16 + 4 * g]);
    const float4 a1 = *reinterpret_cast<const float4*>(&xs[(16 + li) * 36 + 4 * g]);
    const float4 b1 = *reinterpret_cast<const float4*>(&xs[(16 + li) * 36 + 16 + 4 * g]);
    X0 = split16(a0, b0); X1 = split16(a1, b1);
  }

  // ---- 2/3. H chunks (write packed f16 pair) + G accumulation (4-term) ----
  f32x4 d0 = {0, 0, 0, 0}, d1 = {0, 0, 0, 0};
  for (int c = 0; c < 2; ++c) {
#pragma unroll
    for (int j = 0; j < 2; ++j) {
      const int Tl = tl + j;        // chunk-local tile 0..15
      const int T = 16 * c + Tl;    // global tile 0..31
      const f16x8 Whi = __builtin_bit_cast(f16x8, wf[T * 64 + l]);
      const f16x8 Wlo = __builtin_bit_cast(f16x8, wf[(32 + T) * 64 + l]);
      f32x4 a0 = {0, 0, 0, 0}, a1 = {0, 0, 0, 0};
      a0 = MFMA(X0.hi, Whi, a0); a0 = MFMA(X0.hi, Wlo, a0); a0 = MFMA(X0.lo, Whi, a0);
      a1 = MFMA(X1.hi, Whi, a1); a1 = MFMA(X1.hi, Wlo, a1); a1 = MFMA(X1.lo, Whi, a1);
      const float bv = bias[16 * T + li];
      const int col = 16 * Tl + li;
#pragma unroll
      for (int i = 0; i < 4; ++i) {
        const int r0 = 4 * g + i;
        Hc[r0 * 256 + ((((col >> 2) ^ (r0 & 31)) << 2) | (col & 3))] = packh(sigm(a0[i] + bv));
        const int r1 = 16 + 4 * g + i;
        const unsigned pv = (r1 < 28) ? packh(sigm(a1[i] + bv)) : 0u;
        Hc[r1 * 256 + ((((col >> 2) ^ (r1 & 31)) << 2) | (col & 3))] = pv;
      }
    }
    __syncthreads();
    const uint4* H4 = reinterpret_cast<const uint4*>(Hc);
#pragma unroll
    for (int s = 0; s < 2; ++s) {
      const int kk = q + 4 * s;                   // chunk-local 32-col k-step
      const int cg0 = kk * 8 + g, cg1 = kk * 8 + 4 + g;
      const int rA = tr * 16 + li;
      const P16 Af = unpackP(H4[rA * 64 + (cg0 ^ (rA & 31))], H4[rA * 64 + (cg1 ^ (rA & 31))]);
      const int rB0 = li;
      const P16 Bf0 = unpackP(H4[rB0 * 64 + (cg0 ^ (rB0 & 31))], H4[rB0 * 64 + (cg1 ^ (rB0 & 31))]);
      const int rB1 = 16 + li;
      const P16 Bf1 = unpackP(H4[rB1 * 64 + (cg0 ^ (rB1 & 31))], H4[rB1 * 64 + (cg1 ^ (rB1 & 31))]);
      d0 = MFMA(Af.hi, Bf0.hi, d0); d0 = MFMA(Af.hi, Bf0.lo, d0);
      d0 = MFMA(Af.lo, Bf0.hi, d0); d0 = MFMA(Af.lo, Bf0.lo, d0);
      d1 = MFMA(Af.hi, Bf1.hi, d1); d1 = MFMA(Af.hi, Bf1.lo, d1);
      d1 = MFMA(Af.lo, Bf1.hi, d1); d1 = MFMA(Af.lo, Bf1.lo, d1);
    }
    __syncthreads();
  }

  // ---- 4. G reduce across k-quarters (scratch in dead Hc) ----
  float* sc = reinterpret_cast<float*>(Hc);
  if (q != 0) {
    const int idx = ((tr * 3 + (q - 1)) * 64 + l) * 8;
    *reinterpret_cast<float4*>(&sc[idx]) = float4{d0[0], d0[1], d0[2], d0[3]};
    *reinterpret_cast<float4*>(&sc[idx + 4]) = float4{d1[0], d1[1], d1[2], d1[3]};
  }
  __syncthreads();
  if (q == 0) {
#pragma unroll
    for (int p = 0; p < 3; ++p) {
      const int idx = ((tr * 3 + p) * 64 + l) * 8;
      const float4 u = *reinterpret_cast<const float4*>(&sc[idx]);
      const float4 v = *reinterpret_cast<const float4*>(&sc[idx + 4]);
      d0[0] += u.x; d0[1] += u.y; d0[2] += u.z; d0[3] += u.w;
      d1[0] += v.x; d1[1] += v.y; d1[2] += v.z; d1[3] += v.w;
    }
#pragma unroll
    for (int i = 0; i < 4; ++i) {
      const int r = tr * 16 + 4 * g + i;
      if (r < 28) { Gc[r * 32 + li] = d0[i]; Gc[r * 32 + 16 + li] = d1[i]; }
    }
  }
  __syncthreads();

  // ---- 5. solve G Y = x : Gauss-Jordan on wave 0, lane j owns augmented col j ----
  if (tid < 64) {
    const int j = tid;
    float col[28];
#pragma unroll
    for (int r = 0; r < 28; ++r) {
      float v = 0.f;
      if (j < 28)      v = Gc[r * 32 + j];
      else if (j < 56) v = xs[r * 36 + (j - 28)];
      col[r] = v;
    }
#pragma unroll
    for (int k = 0; k < 28; ++k) {
      const float piv = __shfl(col[k], k);
      const float pivinv = 1.0f / piv;
      col[k] *= pivinv;
#pragma unroll
      for (int r2 = 0; r2 < 28; ++r2) {
        if (r2 == k) continue;
        const float m = __shfl(col[r2], k);
        col[r2] -= m * col[k];
      }
    }
    if (j >= 28 && j < 56) {
      const int c2 = j - 28;
#pragma unroll
      for (int r2 = 0; r2 < 28; ++r2) Yt[c2 * 36 + r2] = col[r2];
    }
  }
  __syncthreads();

  // ---- 6. B = H~^T Y : recompute H per tile, MFMA out-fragment == B-operand ----
  P16 Y0, Y1;
  {
    const float4 a0 = *reinterpret_cast<const float4*>(&Yt[li * 36 + 4 * g]);
    const float4 b0 = *reinterpret_cast<const float4*>(&Yt[li * 36 + 16 + 4 * g]);
    const float4 a1 = *reinterpret_cast<const float4*>(&Yt[(16 + li) * 36 + 4 * g]);
    const float4 b1 = *reinterpret_cast<const float4*>(&Yt[(16 + li) * 36 + 16 + 4 * g]);
    Y0 = split16(a0, b0); Y1 = split16(a1, b1);
  }
  float* Bs = reinterpret_cast<float*>(Hc);
  for (int grp = 0; grp < 2; ++grp) {
#pragma unroll
    for (int j = 0; j < 2; ++j) {
      const int T = 16 * grp + tl + j;
      const f16x8 Whi = __builtin_bit_cast(f16x8, wf[T * 64 + l]);
      const f16x8 Wlo = __builtin_bit_cast(f16x8, wf[(32 + T) * 64 + l]);
      f32x4 a0 = {0, 0, 0, 0}, a1 = {0, 0, 0, 0};
      a0 = MFMA(X0.hi, Whi, a0); a0 = MFMA(X0.hi, Wlo, a0); a0 = MFMA(X0.lo, Whi, a0);
      a1 = MFMA(X1.hi, Whi, a1); a1 = MFMA(X1.hi, Wlo, a1); a1 = MFMA(X1.lo, Whi, a1);
      const float bv = bias[16 * T + li];
      f16x8 Bhi, Blo;
#pragma unroll
      for (int i = 0; i < 4; ++i) {
        const float h0 = sigm(a0[i] + bv);
        const _Float16 hh0 = (_Float16)h0;
        Bhi[i] = hh0; Blo[i] = (_Float16)(h0 - (float)hh0);
        const int r1 = 16 + 4 * g + i;
        const float h1 = (r1 < 28) ? sigm(a1[i] + bv) : 0.0f;
        const _Float16 hh1 = (_Float16)h1;
        Bhi[4 + i] = hh1; Blo[4 + i] = (_Float16)(h1 - (float)hh1);
      }
      f32x4 bt0 = {0, 0, 0, 0}, bt1 = {0, 0, 0, 0};
      bt0 = MFMA(Y0.hi, Bhi, bt0); bt0 = MFMA(Y0.hi, Blo, bt0); bt0 = MFMA(Y0.lo, Bhi, bt0);
      bt1 = MFMA(Y1.hi, Bhi, bt1); bt1 = MFMA(Y1.hi, Blo, bt1); bt1 = MFMA(Y1.lo, Bhi, bt1);
      const int hp = 16 * (tl + j) + li;          // 0..255 within group
      *reinterpret_cast<float4*>(&Bs[hp * 28 + 4 * g]) = float4{bt0[0], bt0[1], bt0[2], bt0[3]};
      if (g < 3)
        *reinterpret_cast<float4*>(&Bs[hp * 28 + 16 + 4 * g]) = float4{bt1[0], bt1[1], bt1[2], bt1[3]};
    }
    __syncthreads();
    const float4* Bs4 = reinterpret_cast<const float4*>(Bs);
    float4* Bo4 = reinterpret_cast<float4*>(Bout + (size_t)n * 14336 + grp * 7168);
#pragma unroll
    for (int k2 = 0; k2 < 4; ++k2) {
      const int idx = tid + 512 * k2;
      if (idx < 1792) Bo4[idx] = Bs4[idx];
    }
    __syncthreads();
  }
}

extern "C" void kernel_launch(void* const* d_in, const int* in_sizes, int n_in,
                              void* d_out, int out_size, void* d_ws, size_t ws_size,
                              hipStream_t stream) {
  const float* x = (const float*)d_in[0];
  const float* W = (const float*)d_in[1];
  const float* b = (const float*)d_in[2];
  const int N = in_sizes[0] / 784;               // 4096 samples
  float* Xout = (float*)d_out;                   // [N,1,28,28]
  float* Bout = Xout + (size_t)N * 784;          // [N,1,512,28]
  uint4* wf = (uint4*)d_ws;                      // 65536 B
  prep_wfrag<<<8, 256, 0, stream>>>(W, wf);
  elm_kernel<<<N, THREADS, 0, stream>>>(x, wf, b, Xout, Bout);
}